// Round 17
// baseline (89.384 us; speedup 1.0000x reference)
//
#include <hip/hip_runtime.h>
#include <hip/hip_bf16.h>
#include <math.h>

#define BB 4
#define TT 4096
#define DD 512
#define HH 64
#define TW 128   // TT/32 words

typedef unsigned int u32;
typedef unsigned short u16;
typedef float f32x16 __attribute__((ext_vector_type(16)));
typedef __bf16 bf16x8 __attribute__((ext_vector_type(8)));

#define SC 0.18033688011112042f  /* 0.125 * log2(e), folded into Q at proj */

static __device__ __forceinline__ u16 f2b(float f) {
    __hip_bfloat16 h = __float2bfloat16(f);
    return __builtin_bit_cast(u16, h);
}
static __device__ __forceinline__ float b2f(u16 x) {
    return __builtin_bit_cast(float, (u32)x << 16);
}
static __device__ __forceinline__ u32 pk2(float a, float b) {
    return (u32)f2b(a) | ((u32)f2b(b) << 16);
}
static __device__ __forceinline__ bf16x8 ldf(const u16* p) {
    uint4 u = *(const uint4*)p;
    return __builtin_bit_cast(bf16x8, u);
}
// swap high 32 lanes of a with low 32 lanes of b (both results used)
static __device__ __forceinline__ void swap32(u32& a, u32& b) {
    asm("v_permlane32_swap_b32 %0, %1" : "+v"(a), "+v"(b));
}

// Fragment-order layouts (MFMA 32x32x16 fragment: lane&31 = row/col-of-32,
// lane>>5 = k-half, 8 consecutive k per lane):
//   QF/KF: [b*128 + tile][kt=0..3][lane][8 u16]  (row = t, k = d); QF pre-scaled
//   VF:    [b*128 + tile][hg*2+k2][lane][8 u16]  (col = h, k = i-local); VF2 = scaled
//   bits2:  [jt][i]  word = 32 j-bits for row i
//   bitsTT: [it][j]  word = 32 i-bits for col j
//
// Pipeline: wtr -> pp (pack || proj) -> stats (+V-scale) -> out.
// Pack: wave owns 32 rows x 64 cols. The 32 coalesced row loads are INLINE
// ASM global_load_dword (ordered volatile asm -> all 32 issue before the one
// s_waitcnt vmcnt(0)) -- r15/r16 showed compiler hints cannot stop the
// allocator from sinking C++ loads into the ballot loop (VGPR stayed 32,
// one load in flight). Ballot results are distributed to lanes branch-free
// via cndmask; all stores coalesced.
// XCD pinning (stats/out): b = (bid&7)>>1 -> batch b owns XCD pair {2b,2b+1}.

// ---------------------------------------------------------------------------
// W transpose: fp32 W[512][64] x3 -> bf16 Wt[3][64][512]. 24 blocks.
// ---------------------------------------------------------------------------
__global__ __launch_bounds__(256) void wtr_kernel(const float* __restrict__ Wq,
                                                  const float* __restrict__ Wk,
                                                  const float* __restrict__ Wv,
                                                  u16* __restrict__ Wt) {
    const int wb = blockIdx.x;            // 0..23
    const int m = wb >> 3, sub = wb & 7;
    const float* W = (m == 0) ? Wq : (m == 1) ? Wk : Wv;
    const int t = threadIdx.x;
    const int n = sub * 8 + (t >> 5);
    const int k0 = (t & 31) * 16;
    u16 buf[16];
#pragma unroll
    for (int k = 0; k < 16; ++k) buf[k] = f2b(W[(size_t)(k0 + k) * HH + n]);
    uint4* dst = (uint4*)(Wt + ((size_t)m * 64 + n) * DD + k0);
    dst[0] = *(uint4*)buf;
    dst[1] = *(uint4*)(buf + 8);
}

// ---------------------------------------------------------------------------
// pp: heterogeneous launch. Blocks 0..255 = QKV projection (384 thr, 6 waves);
// blocks 256..1621 = dag pack (6 wave-units per block, asm-load-then-ballot).
// ---------------------------------------------------------------------------
__global__ __launch_bounds__(384, 1) void pp_kernel(const float* __restrict__ X,
                                                    const u16* __restrict__ Wt,
                                                    u16* __restrict__ QF,
                                                    u16* __restrict__ KF,
                                                    u16* __restrict__ VF,
                                                    const int* __restrict__ dag,
                                                    u32* __restrict__ bits2,
                                                    u32* __restrict__ bitsTT) {
    if (blockIdx.x >= 256) {
        // ------------------ pack path ------------------
        const int w = threadIdx.x >> 6, lane = threadIdx.x & 63;
        const int unit = (blockIdx.x - 256) * 6 + w;
        if (unit >= 8192) return;
        const int i32r = unit >> 6;       // 0..127 row-group (32 rows)
        const int j64 = unit & 63;        // 0..63 col-group (64 cols)
        const int i0 = i32r * 32, j0 = j64 * 64;
        const int* p = dag + (size_t)i0 * TT + j0 + lane;
        // PHASE 1: 32 coalesced row loads via inline asm -> all in flight,
        // a single vmcnt(0) drain (no per-row serialization possible).
        int vals[32];
#pragma unroll
        for (int r = 0; r < 32; ++r) {
            const int* addr = p + (size_t)r * TT;
            asm volatile("global_load_dword %0, %1, off"
                         : "=v"(vals[r]) : "v"(addr));
        }
        asm volatile("s_waitcnt vmcnt(0)" ::: "memory");
        __builtin_amdgcn_sched_barrier(0);
        // PHASE 2: ballots; distribute row-words to lanes branch-free.
        u32 colw = 0, rowsel = 0;
        const bool lowhalf = (lane < 32);
        const int lsel = lane & 31;
#pragma unroll
        for (int r = 0; r < 32; ++r) {
            unsigned long long m = __ballot(vals[r] != 0);
            colw |= (vals[r] != 0 ? 1u : 0u) << r;
            u32 lom = (u32)m, him = (u32)(m >> 32);
            u32 pick = lowhalf ? lom : him;
            rowsel = (lsel == r) ? pick : rowsel;
        }
        // lane<32: bits2 low-word of row (lane), lane>=32: high-word of row (lane-32)
        bits2[(size_t)(j64 * 2 + (lane >> 5)) * TT + i0 + lsel] = rowsel;
        bitsTT[(size_t)i32r * TT + j0 + lane] = colw;  // coalesced 256 B
        return;
    }
    // ------------------ proj path ------------------
    const int w = threadIdx.x >> 6, lane = threadIdx.x & 63;
    const int m = w % 3, rg = w / 3;
    const int l31 = lane & 31, hf = lane >> 5;
    const int tile = blockIdx.x * 2 + rg;       // global 32-row tile id
    const int row0 = tile * 32;
    const float* xr = X + (size_t)(row0 + l31) * DD + hf * 8;
    const u16* wbase = Wt + (size_t)m * 64 * DD + hf * 8;

    f32x16 acc[2] = {};

    for (int kt = 0; kt < 32; ++kt) {
        float4 x0 = *(const float4*)(xr + kt * 16);
        float4 x1 = *(const float4*)(xr + kt * 16 + 4);
        uint4 aw;
        aw.x = pk2(x0.x, x0.y);
        aw.y = pk2(x0.z, x0.w);
        aw.z = pk2(x1.x, x1.y);
        aw.w = pk2(x1.z, x1.w);
        bf16x8 xa = __builtin_bit_cast(bf16x8, aw);
        const u16* wk = wbase + kt * 16;
#pragma unroll
        for (int nt = 0; nt < 2; ++nt) {
            bf16x8 wb = ldf(wk + (size_t)(nt * 32 + l31) * DD);
            acc[nt] = __builtin_amdgcn_mfma_f32_32x32x16_bf16(xa, wb, acc[nt], 0, 0, 0);
        }
    }
    const float sc = (m == 0) ? SC : 1.0f;
    if (m < 2) {
        // A-fragment order: row = t (= row0+rl), k = d (= nt*32+l31)
        u16* dst = (m == 0) ? QF : KF;
        const int kth = l31 >> 4, hfp = (l31 >> 3) & 1, e = l31 & 7;
#pragma unroll
        for (int nt = 0; nt < 2; ++nt)
#pragma unroll
            for (int r = 0; r < 16; ++r) {
                int rl = (r & 3) + 8 * (r >> 2) + 4 * hf;
                dst[(size_t)tile * 2048 + (nt * 2 + kth) * 512 + (rl + hfp * 32) * 8 + e]
                    = f2b(acc[nt][r] * sc);
            }
    } else {
        // B-fragment order: col = h (= nt*32+l31), k = i-local (= rl)
#pragma unroll
        for (int nt = 0; nt < 2; ++nt)
#pragma unroll
            for (int r = 0; r < 16; ++r) {
                int rl = (r & 3) + 8 * (r >> 2) + 4 * hf;
                VF[(size_t)tile * 2048 + (nt * 2 + (rl >> 4)) * 512
                   + (l31 + ((rl >> 3) & 1) * 32) * 8 + (rl & 7)] = f2b(acc[nt][r]);
            }
    }
}

// ---------------------------------------------------------------------------
// Stats + V-scale: for TWO adjacent 32-i tiles, L_i = sum_j mask*exp2(S);
// then scale both VF tiles into VF2 by c_i = 1/L_i (0 if dead).
// Block 512 thr (8 waves), 8-way j-split. Grid 256. XCD-pinned (b pair).
// ---------------------------------------------------------------------------
__global__ __launch_bounds__(512, 2) void stats_kernel(const u16* __restrict__ QF,
                                                       const u16* __restrict__ KF,
                                                       const u32* __restrict__ bits2,
                                                       const u16* __restrict__ VF,
                                                       u16* __restrict__ VF2) {
    __shared__ float Lsh[8][128];
    __shared__ float cSh[64];
    const int bid = blockIdx.x;
    const int b = (bid & 7) >> 1;
    const int u = (bid & 1) * 32 + (bid >> 3);
    const int itg0 = u * 2;
    const int i0 = itg0 * 32;
    const int w = threadIdx.x >> 6, lane = threadIdx.x & 63;
    const int l31 = lane & 31, hf = lane >> 5;

    bf16x8 qfA[4], qfB[4];
    const u16* qbase = QF + (size_t)(b * 128 + itg0) * 2048 + lane * 8;
#pragma unroll
    for (int kt = 0; kt < 4; ++kt) {
        qfA[kt] = ldf(qbase + kt * 512);
        qfB[kt] = ldf(qbase + 2048 + kt * 512);
    }

    const u16* kf0 = KF + (size_t)b * 128 * 2048 + lane * 8;

    float LpA = 0.f, LpB = 0.f;
    for (int t = 0; t < 16; ++t) {
        const int jt = w + t * 8;
        const u16* kb = kf0 + (size_t)jt * 2048;
        u32 mwA = bits2[(size_t)jt * TT + i0 + l31];
        u32 mwB = bits2[(size_t)jt * TT + i0 + 32 + l31];

        bf16x8 k0 = ldf(kb), k1 = ldf(kb + 512), k2 = ldf(kb + 1024), k3 = ldf(kb + 1536);
        __builtin_amdgcn_s_setprio(1);
        f32x16 sA = {}, sB = {};
        sA = __builtin_amdgcn_mfma_f32_32x32x16_bf16(k0, qfA[0], sA, 0, 0, 0);
        sB = __builtin_amdgcn_mfma_f32_32x32x16_bf16(k0, qfB[0], sB, 0, 0, 0);
        sA = __builtin_amdgcn_mfma_f32_32x32x16_bf16(k1, qfA[1], sA, 0, 0, 0);
        sB = __builtin_amdgcn_mfma_f32_32x32x16_bf16(k1, qfB[1], sB, 0, 0, 0);
        sA = __builtin_amdgcn_mfma_f32_32x32x16_bf16(k2, qfA[2], sA, 0, 0, 0);
        sB = __builtin_amdgcn_mfma_f32_32x32x16_bf16(k2, qfB[2], sB, 0, 0, 0);
        sA = __builtin_amdgcn_mfma_f32_32x32x16_bf16(k3, qfA[3], sA, 0, 0, 0);
        sB = __builtin_amdgcn_mfma_f32_32x32x16_bf16(k3, qfB[3], sB, 0, 0, 0);
        __builtin_amdgcn_s_setprio(0);
        u32 mrA = __builtin_amdgcn_alignbit(mwA, mwA, hf * 4);  // rotr by 4*hf
        u32 mrB = __builtin_amdgcn_alignbit(mwB, mwB, hf * 4);
#pragma unroll
        for (int r = 0; r < 16; ++r) {
            const int pos = (r & 3) + 8 * (r >> 2);
            float eA = __builtin_amdgcn_exp2f(sA[r]);
            float eB = __builtin_amdgcn_exp2f(sB[r]);
            LpA += ((mrA >> pos) & 1) ? eA : 0.f;
            LpB += ((mrB >> pos) & 1) ? eB : 0.f;
        }
    }
    Lsh[w][lane] = LpA;
    Lsh[w][64 + lane] = LpB;
    __syncthreads();
    if (threadIdx.x < 64) {
        const int g = threadIdx.x >> 5, il = threadIdx.x & 31;
        float L = 0.f;
#pragma unroll
        for (int q = 0; q < 8; ++q) L += Lsh[q][g * 64 + il] + Lsh[q][g * 64 + il + 32];
        cSh[g * 32 + il] = (L > 0.f) ? 1.f / L : 0.f;
    }
    __syncthreads();
    // scale the block's two VF tiles (512 uint4) into VF2; 1 uint4/thread
    {
        const int tl = threadIdx.x >> 8;          // 0..1 tile-local
        const int rem = threadIdx.x & 255;
        const int q = rem >> 6, ln = rem & 63;
        const int ib = tl * 32 + (q & 1) * 16 + (ln >> 5) * 8;
        float4 c0 = *(const float4*)&cSh[ib];
        float4 c1 = *(const float4*)&cSh[ib + 4];
        const size_t off = (size_t)(b * 128 + itg0 + tl) * 2048 + q * 512 + ln * 8;
        uint4 v = *(const uint4*)(VF + off);
        u16* ve = (u16*)&v;
        ve[0] = f2b(b2f(ve[0]) * c0.x);
        ve[1] = f2b(b2f(ve[1]) * c0.y);
        ve[2] = f2b(b2f(ve[2]) * c0.z);
        ve[3] = f2b(b2f(ve[3]) * c0.w);
        ve[4] = f2b(b2f(ve[4]) * c1.x);
        ve[5] = f2b(b2f(ve[5]) * c1.y);
        ve[6] = f2b(b2f(ve[6]) * c1.z);
        ve[7] = f2b(b2f(ve[7]) * c1.w);
        *(uint4*)(VF2 + off) = v;
    }
}

// ---------------------------------------------------------------------------
// Output: TWO adjacent 32-j tiles per block; each Q/V load feeds both S/PV
// chains. Block 512 thr (8 waves), 8-way i-split. Grid 256. XCD-pinned.
// ---------------------------------------------------------------------------
__global__ __launch_bounds__(512, 2) void out_kernel(const u16* __restrict__ QF,
                                                     const u16* __restrict__ KF,
                                                     const u16* __restrict__ VF2,
                                                     const u32* __restrict__ bitsTT,
                                                     float* __restrict__ out) {
    __shared__ float red[2][4][2048];
    const int bid = blockIdx.x;
    const int b = (bid & 7) >> 1;
    const int u = (bid & 1) * 32 + (bid >> 3);
    const int jt0 = u * 2;
    const int j0 = jt0 * 32;
    const int w = threadIdx.x >> 6, lane = threadIdx.x & 63;
    const int l31 = lane & 31, hf = lane >> 5;

    bf16x8 kfA[4], kfB[4];
    const u16* kbase = KF + (size_t)(b * 128 + jt0) * 2048 + lane * 8;
#pragma unroll
    for (int kt = 0; kt < 4; ++kt) {
        kfA[kt] = ldf(kbase + kt * 512);
        kfB[kt] = ldf(kbase + 2048 + kt * 512);
    }

    const u16* qf0 = QF + (size_t)b * 128 * 2048 + lane * 8;
    const u16* vf0 = VF2 + (size_t)b * 128 * 2048 + lane * 8;

    f32x16 accA0 = {}, accA1 = {}, accB0 = {}, accB1 = {};

    for (int t = 0; t < 16; ++t) {
        const int it = w + t * 8;
        const u16* qb = qf0 + (size_t)it * 2048;
        const u16* vb = vf0 + (size_t)it * 2048;
        u32 mwA = bitsTT[(size_t)it * TT + j0 + l31];
        u32 mwB = bitsTT[(size_t)it * TT + j0 + 32 + l31];

        bf16x8 q0 = ldf(qb), q1 = ldf(qb + 512), q2 = ldf(qb + 1024), q3 = ldf(qb + 1536);
        __builtin_amdgcn_s_setprio(1);
        f32x16 sA = {}, sB = {};
        sA = __builtin_amdgcn_mfma_f32_32x32x16_bf16(q0, kfA[0], sA, 0, 0, 0);
        sB = __builtin_amdgcn_mfma_f32_32x32x16_bf16(q0, kfB[0], sB, 0, 0, 0);
        sA = __builtin_amdgcn_mfma_f32_32x32x16_bf16(q1, kfA[1], sA, 0, 0, 0);
        sB = __builtin_amdgcn_mfma_f32_32x32x16_bf16(q1, kfB[1], sB, 0, 0, 0);
        sA = __builtin_amdgcn_mfma_f32_32x32x16_bf16(q2, kfA[2], sA, 0, 0, 0);
        sB = __builtin_amdgcn_mfma_f32_32x32x16_bf16(q2, kfB[2], sB, 0, 0, 0);
        sA = __builtin_amdgcn_mfma_f32_32x32x16_bf16(q3, kfA[3], sA, 0, 0, 0);
        sB = __builtin_amdgcn_mfma_f32_32x32x16_bf16(q3, kfB[3], sB, 0, 0, 0);
        __builtin_amdgcn_s_setprio(0);

        u32 mrA = __builtin_amdgcn_alignbit(mwA, mwA, hf * 4);  // rotr by 4*hf
        u32 mrB = __builtin_amdgcn_alignbit(mwB, mwB, hf * 4);

        float pA[16], pB[16];
#pragma unroll
        for (int r = 0; r < 16; ++r) {
            const int pos = (r & 3) + 8 * (r >> 2);
            float eA = __builtin_amdgcn_exp2f(sA[r]);
            float eB = __builtin_amdgcn_exp2f(sB[r]);
            pA[r] = ((mrA >> pos) & 1) ? eA : 0.f;
            pB[r] = ((mrB >> pos) & 1) ? eB : 0.f;
        }

        bf16x8 v00 = ldf(vb), v01 = ldf(vb + 512), v10 = ldf(vb + 1024), v11 = ldf(vb + 1536);

#pragma unroll
        for (int k2 = 0; k2 < 2; ++k2) {
            u32 aA  = pk2(pA[8 * k2 + 0], pA[8 * k2 + 1]);
            u32 bA  = pk2(pA[8 * k2 + 2], pA[8 * k2 + 3]);
            u32 cA  = pk2(pA[8 * k2 + 4], pA[8 * k2 + 5]);
            u32 dA  = pk2(pA[8 * k2 + 6], pA[8 * k2 + 7]);
            swap32(aA, cA);
            swap32(bA, dA);
            uint4 awA = {aA, bA, cA, dA};
            bf16x8 paA = __builtin_bit_cast(bf16x8, awA);
            u32 aB  = pk2(pB[8 * k2 + 0], pB[8 * k2 + 1]);
            u32 bB  = pk2(pB[8 * k2 + 2], pB[8 * k2 + 3]);
            u32 cB2 = pk2(pB[8 * k2 + 4], pB[8 * k2 + 5]);
            u32 dB  = pk2(pB[8 * k2 + 6], pB[8 * k2 + 7]);
            swap32(aB, cB2);
            swap32(bB, dB);
            uint4 awB = {aB, bB, cB2, dB};
            bf16x8 paB = __builtin_bit_cast(bf16x8, awB);
            bf16x8 v0 = (k2 == 0) ? v00 : v01;
            bf16x8 v1 = (k2 == 0) ? v10 : v11;
            __builtin_amdgcn_s_setprio(1);
            accA0 = __builtin_amdgcn_mfma_f32_32x32x16_bf16(paA, v0, accA0, 0, 0, 0);
            accB0 = __builtin_amdgcn_mfma_f32_32x32x16_bf16(paB, v0, accB0, 0, 0, 0);
            accA1 = __builtin_amdgcn_mfma_f32_32x32x16_bf16(paA, v1, accA1, 0, 0, 0);
            accB1 = __builtin_amdgcn_mfma_f32_32x32x16_bf16(paB, v1, accB1, 0, 0, 0);
            __builtin_amdgcn_s_setprio(0);
        }
    }

    // staged reduction per j-tile: 8 waves -> 4 -> final sum by all threads
    if (w >= 4) {
#pragma unroll
        for (int r = 0; r < 16; ++r) {
            int jl = (r & 3) + 8 * (r >> 2) + 4 * hf;
            red[0][w - 4][jl * 64 + l31] = accA0[r];
            red[0][w - 4][jl * 64 + 32 + l31] = accA1[r];
            red[1][w - 4][jl * 64 + l31] = accB0[r];
            red[1][w - 4][jl * 64 + 32 + l31] = accB1[r];
        }
    }
    __syncthreads();
    if (w < 4) {
#pragma unroll
        for (int r = 0; r < 16; ++r) {
            int jl = (r & 3) + 8 * (r >> 2) + 4 * hf;
            red[0][w][jl * 64 + l31] += accA0[r];
            red[0][w][jl * 64 + 32 + l31] += accA1[r];
            red[1][w][jl * 64 + l31] += accB0[r];
            red[1][w][jl * 64 + 32 + l31] += accB1[r];
        }
    }
    __syncthreads();
    {
        const int idx = threadIdx.x * 8;          // [0, 4096)
        const int g3 = idx >> 11, e = idx & 2047;
        float vv[8];
#pragma unroll
        for (int q = 0; q < 8; ++q) {
            int ee = e + q;
            float v = red[g3][0][ee] + red[g3][1][ee] + red[g3][2][ee] + red[g3][3][ee];
            vv[q] = v / (1.f + __expf(-v));
        }
        const int jl = e >> 6, hc = e & 63;
        float* dst = out + ((size_t)b * TT + (jt0 + g3) * 32 + jl) * HH + hc;
        *(float4*)dst = make_float4(vv[0], vv[1], vv[2], vv[3]);
        *(float4*)(dst + 4) = make_float4(vv[4], vv[5], vv[6], vv[7]);
    }
}

// ---------------------------------------------------------------------------
extern "C" void kernel_launch(void* const* d_in, const int* in_sizes, int n_in,
                              void* d_out, int out_size, void* d_ws, size_t ws_size,
                              hipStream_t stream) {
    const float* X  = (const float*)d_in[0];
    const int*  dag = (const int*)d_in[1];
    const float* Wk = (const float*)d_in[2];
    const float* Wq = (const float*)d_in[3];
    const float* Wv = (const float*)d_in[4];
    float* out = (float*)d_out;

    char* ws = (char*)d_ws;
    u16*   QF    = (u16*)ws;                                // 0..2 MB (A-frag, pre-scaled)
    u16*   KF    = (u16*)(ws + (2u << 20));                 // 2..4 MB (A-frag)
    u16*   VF    = (u16*)(ws + (4u << 20));                 // 4..6 MB (B-frag, unscaled)
    u16*   VF2   = (u16*)(ws + (6u << 20));                 // 6..8 MB (B-frag, scaled)
    u32*   bits2 = (u32*)(ws + (8u << 20));                 // 8..10 MB  [jt][i]
    u32*   bitsTT= (u32*)(ws + (10u << 20));                // 10..12 MB [it][j]
    u16*   Wt    = (u16*)(ws + (12u << 20));                // 192 KB

    wtr_kernel<<<24, 256, 0, stream>>>(Wq, Wk, Wv, Wt);
    pp_kernel<<<256 + 1366, 384, 0, stream>>>(X, Wt, QF, KF, VF, dag, bits2, bitsTT);
    stats_kernel<<<256, 512, 0, stream>>>(QF, KF, bits2, VF, VF2);
    out_kernel<<<256, 512, 0, stream>>>(QF, KF, VF2, bitsTT, out);
}

// Round 18
// 87.588 us; speedup vs baseline: 1.0205x; 1.0205x over previous
//
#include <hip/hip_runtime.h>
#include <hip/hip_bf16.h>
#include <math.h>

#define BB 4
#define TT 4096
#define DD 512
#define HH 64
#define TW 128   // TT/32 words

typedef unsigned int u32;
typedef unsigned short u16;
typedef float f32x16 __attribute__((ext_vector_type(16)));
typedef __bf16 bf16x8 __attribute__((ext_vector_type(8)));

#define SC 0.18033688011112042f  /* 0.125 * log2(e), folded into Q at proj */

#define GLB_CP(x) ((const __attribute__((address_space(1))) void*)(x))
#define LDS_CP(x) ((__attribute__((address_space(3))) void*)(x))

static __device__ __forceinline__ u16 f2b(float f) {
    __hip_bfloat16 h = __float2bfloat16(f);
    return __builtin_bit_cast(u16, h);
}
static __device__ __forceinline__ float b2f(u16 x) {
    return __builtin_bit_cast(float, (u32)x << 16);
}
static __device__ __forceinline__ u32 pk2(float a, float b) {
    return (u32)f2b(a) | ((u32)f2b(b) << 16);
}
static __device__ __forceinline__ bf16x8 ldf(const u16* p) {
    uint4 u = *(const uint4*)p;
    return __builtin_bit_cast(bf16x8, u);
}
// swap high 32 lanes of a with low 32 lanes of b (both results used)
static __device__ __forceinline__ void swap32(u32& a, u32& b) {
    asm("v_permlane32_swap_b32 %0, %1" : "+v"(a), "+v"(b));
}

// Fragment-order layouts (MFMA 32x32x16 fragment: lane&31 = row/col-of-32,
// lane>>5 = k-half, 8 consecutive k per lane):
//   QF/KF: [b*128 + tile][kt=0..3][lane][8 u16]  (row = t, k = d); QF pre-scaled
//   VF:    [b*128 + tile][hg*2+k2][lane][8 u16]  (col = h, k = i-local); VF2 = scaled
//   bits2:  [jt][i]  word = 32 j-bits for row i
//   bitsTT: [it][j]  word = 32 i-bits for col j
//
// Pipeline: wtr -> pp (pack || proj) -> stats (+V-scale) -> out.
// Pack: wave owns 32 rows x 64 cols. The 32 coalesced row loads go through
// __builtin_amdgcn_global_load_lds (async, NO VGPR destination) -- the only
// load type the waitcnt pass batch-pipelines (r15-r17 proved reg-dest loads
// get a conservative per-load vmcnt drain). One vmcnt(0), then ballots read
// the staged rows from LDS (conflict-free).
// XCD pinning (stats/out): b = (bid&7)>>1 -> batch b owns XCD pair {2b,2b+1}.

// ---------------------------------------------------------------------------
// W transpose: fp32 W[512][64] x3 -> bf16 Wt[3][64][512]. 24 blocks.
// ---------------------------------------------------------------------------
__global__ __launch_bounds__(256) void wtr_kernel(const float* __restrict__ Wq,
                                                  const float* __restrict__ Wk,
                                                  const float* __restrict__ Wv,
                                                  u16* __restrict__ Wt) {
    const int wb = blockIdx.x;            // 0..23
    const int m = wb >> 3, sub = wb & 7;
    const float* W = (m == 0) ? Wq : (m == 1) ? Wk : Wv;
    const int t = threadIdx.x;
    const int n = sub * 8 + (t >> 5);
    const int k0 = (t & 31) * 16;
    u16 buf[16];
#pragma unroll
    for (int k = 0; k < 16; ++k) buf[k] = f2b(W[(size_t)(k0 + k) * HH + n]);
    uint4* dst = (uint4*)(Wt + ((size_t)m * 64 + n) * DD + k0);
    dst[0] = *(uint4*)buf;
    dst[1] = *(uint4*)(buf + 8);
}

// ---------------------------------------------------------------------------
// pp: heterogeneous launch. Blocks 0..255 = QKV projection (384 thr, 6 waves);
// blocks 256..1621 = dag pack (6 wave-units per block, global_load_lds batch).
// ---------------------------------------------------------------------------
__global__ __launch_bounds__(384, 1) void pp_kernel(const float* __restrict__ X,
                                                    const u16* __restrict__ Wt,
                                                    u16* __restrict__ QF,
                                                    u16* __restrict__ KF,
                                                    u16* __restrict__ VF,
                                                    const int* __restrict__ dag,
                                                    u32* __restrict__ bits2,
                                                    u32* __restrict__ bitsTT) {
    __shared__ int lbuf[6][2048];      // 6 waves x (32 rows x 64 cols) = 48 KB
    if (blockIdx.x >= 256) {
        // ------------------ pack path ------------------
        const int w = threadIdx.x >> 6, lane = threadIdx.x & 63;
        const int unit = (blockIdx.x - 256) * 6 + w;
        if (unit >= 8192) return;
        const int i32r = unit >> 6;       // 0..127 row-group (32 rows)
        const int j64 = unit & 63;        // 0..63 col-group (64 cols)
        const int i0 = i32r * 32, j0 = j64 * 64;
        const int* p = dag + (size_t)i0 * TT + j0 + lane;
        int* myb = &lbuf[w][0];
        // PHASE 1: 32 async global->LDS row stages, ALL in flight, one drain.
#pragma unroll
        for (int r = 0; r < 32; ++r) {
            __builtin_amdgcn_global_load_lds(GLB_CP(p + (size_t)r * TT),
                                             LDS_CP(myb + r * 64), 4, 0, 0);
        }
        asm volatile("s_waitcnt vmcnt(0)" ::: "memory");
        __builtin_amdgcn_sched_barrier(0);
        // PHASE 2: ballots from LDS; distribute row-words branch-free.
        u32 colw = 0, rowsel = 0;
        const bool lowhalf = (lane < 32);
        const int lsel = lane & 31;
#pragma unroll
        for (int r = 0; r < 32; ++r) {
            int v = myb[r * 64 + lane];
            unsigned long long m = __ballot(v != 0);
            colw |= (v != 0 ? 1u : 0u) << r;
            u32 pick = lowhalf ? (u32)m : (u32)(m >> 32);
            rowsel = (lsel == r) ? pick : rowsel;
        }
        // lane<32: bits2 low-word of row (lane); lane>=32: high-word
        bits2[(size_t)(j64 * 2 + (lane >> 5)) * TT + i0 + lsel] = rowsel;
        bitsTT[(size_t)i32r * TT + j0 + lane] = colw;  // coalesced 256 B
        return;
    }
    // ------------------ proj path ------------------
    const int w = threadIdx.x >> 6, lane = threadIdx.x & 63;
    const int m = w % 3, rg = w / 3;
    const int l31 = lane & 31, hf = lane >> 5;
    const int tile = blockIdx.x * 2 + rg;       // global 32-row tile id
    const int row0 = tile * 32;
    const float* xr = X + (size_t)(row0 + l31) * DD + hf * 8;
    const u16* wbase = Wt + (size_t)m * 64 * DD + hf * 8;

    f32x16 acc[2] = {};

    for (int kt = 0; kt < 32; ++kt) {
        float4 x0 = *(const float4*)(xr + kt * 16);
        float4 x1 = *(const float4*)(xr + kt * 16 + 4);
        uint4 aw;
        aw.x = pk2(x0.x, x0.y);
        aw.y = pk2(x0.z, x0.w);
        aw.z = pk2(x1.x, x1.y);
        aw.w = pk2(x1.z, x1.w);
        bf16x8 xa = __builtin_bit_cast(bf16x8, aw);
        const u16* wk = wbase + kt * 16;
#pragma unroll
        for (int nt = 0; nt < 2; ++nt) {
            bf16x8 wb = ldf(wk + (size_t)(nt * 32 + l31) * DD);
            acc[nt] = __builtin_amdgcn_mfma_f32_32x32x16_bf16(xa, wb, acc[nt], 0, 0, 0);
        }
    }
    const float sc = (m == 0) ? SC : 1.0f;
    if (m < 2) {
        // A-fragment order: row = t (= row0+rl), k = d (= nt*32+l31)
        u16* dst = (m == 0) ? QF : KF;
        const int kth = l31 >> 4, hfp = (l31 >> 3) & 1, e = l31 & 7;
#pragma unroll
        for (int nt = 0; nt < 2; ++nt)
#pragma unroll
            for (int r = 0; r < 16; ++r) {
                int rl = (r & 3) + 8 * (r >> 2) + 4 * hf;
                dst[(size_t)tile * 2048 + (nt * 2 + kth) * 512 + (rl + hfp * 32) * 8 + e]
                    = f2b(acc[nt][r] * sc);
            }
    } else {
        // B-fragment order: col = h (= nt*32+l31), k = i-local (= rl)
#pragma unroll
        for (int nt = 0; nt < 2; ++nt)
#pragma unroll
            for (int r = 0; r < 16; ++r) {
                int rl = (r & 3) + 8 * (r >> 2) + 4 * hf;
                VF[(size_t)tile * 2048 + (nt * 2 + (rl >> 4)) * 512
                   + (l31 + ((rl >> 3) & 1) * 32) * 8 + (rl & 7)] = f2b(acc[nt][r]);
            }
    }
}

// ---------------------------------------------------------------------------
// Stats + V-scale: for TWO adjacent 32-i tiles, L_i = sum_j mask*exp2(S);
// then scale both VF tiles into VF2 by c_i = 1/L_i (0 if dead).
// Block 512 thr (8 waves), 8-way j-split. Grid 256. XCD-pinned (b pair).
// ---------------------------------------------------------------------------
__global__ __launch_bounds__(512, 2) void stats_kernel(const u16* __restrict__ QF,
                                                       const u16* __restrict__ KF,
                                                       const u32* __restrict__ bits2,
                                                       const u16* __restrict__ VF,
                                                       u16* __restrict__ VF2) {
    __shared__ float Lsh[8][128];
    __shared__ float cSh[64];
    const int bid = blockIdx.x;
    const int b = (bid & 7) >> 1;
    const int u = (bid & 1) * 32 + (bid >> 3);
    const int itg0 = u * 2;
    const int i0 = itg0 * 32;
    const int w = threadIdx.x >> 6, lane = threadIdx.x & 63;
    const int l31 = lane & 31, hf = lane >> 5;

    bf16x8 qfA[4], qfB[4];
    const u16* qbase = QF + (size_t)(b * 128 + itg0) * 2048 + lane * 8;
#pragma unroll
    for (int kt = 0; kt < 4; ++kt) {
        qfA[kt] = ldf(qbase + kt * 512);
        qfB[kt] = ldf(qbase + 2048 + kt * 512);
    }

    const u16* kf0 = KF + (size_t)b * 128 * 2048 + lane * 8;

    float LpA = 0.f, LpB = 0.f;
    for (int t = 0; t < 16; ++t) {
        const int jt = w + t * 8;
        const u16* kb = kf0 + (size_t)jt * 2048;
        u32 mwA = bits2[(size_t)jt * TT + i0 + l31];
        u32 mwB = bits2[(size_t)jt * TT + i0 + 32 + l31];

        bf16x8 k0 = ldf(kb), k1 = ldf(kb + 512), k2 = ldf(kb + 1024), k3 = ldf(kb + 1536);
        __builtin_amdgcn_s_setprio(1);
        f32x16 sA = {}, sB = {};
        sA = __builtin_amdgcn_mfma_f32_32x32x16_bf16(k0, qfA[0], sA, 0, 0, 0);
        sB = __builtin_amdgcn_mfma_f32_32x32x16_bf16(k0, qfB[0], sB, 0, 0, 0);
        sA = __builtin_amdgcn_mfma_f32_32x32x16_bf16(k1, qfA[1], sA, 0, 0, 0);
        sB = __builtin_amdgcn_mfma_f32_32x32x16_bf16(k1, qfB[1], sB, 0, 0, 0);
        sA = __builtin_amdgcn_mfma_f32_32x32x16_bf16(k2, qfA[2], sA, 0, 0, 0);
        sB = __builtin_amdgcn_mfma_f32_32x32x16_bf16(k2, qfB[2], sB, 0, 0, 0);
        sA = __builtin_amdgcn_mfma_f32_32x32x16_bf16(k3, qfA[3], sA, 0, 0, 0);
        sB = __builtin_amdgcn_mfma_f32_32x32x16_bf16(k3, qfB[3], sB, 0, 0, 0);
        __builtin_amdgcn_s_setprio(0);
        u32 mrA = __builtin_amdgcn_alignbit(mwA, mwA, hf * 4);  // rotr by 4*hf
        u32 mrB = __builtin_amdgcn_alignbit(mwB, mwB, hf * 4);
#pragma unroll
        for (int r = 0; r < 16; ++r) {
            const int pos = (r & 3) + 8 * (r >> 2);
            float eA = __builtin_amdgcn_exp2f(sA[r]);
            float eB = __builtin_amdgcn_exp2f(sB[r]);
            LpA += ((mrA >> pos) & 1) ? eA : 0.f;
            LpB += ((mrB >> pos) & 1) ? eB : 0.f;
        }
    }
    Lsh[w][lane] = LpA;
    Lsh[w][64 + lane] = LpB;
    __syncthreads();
    if (threadIdx.x < 64) {
        const int g = threadIdx.x >> 5, il = threadIdx.x & 31;
        float L = 0.f;
#pragma unroll
        for (int q = 0; q < 8; ++q) L += Lsh[q][g * 64 + il] + Lsh[q][g * 64 + il + 32];
        cSh[g * 32 + il] = (L > 0.f) ? 1.f / L : 0.f;
    }
    __syncthreads();
    // scale the block's two VF tiles (512 uint4) into VF2; 1 uint4/thread
    {
        const int tl = threadIdx.x >> 8;          // 0..1 tile-local
        const int rem = threadIdx.x & 255;
        const int q = rem >> 6, ln = rem & 63;
        const int ib = tl * 32 + (q & 1) * 16 + (ln >> 5) * 8;
        float4 c0 = *(const float4*)&cSh[ib];
        float4 c1 = *(const float4*)&cSh[ib + 4];
        const size_t off = (size_t)(b * 128 + itg0 + tl) * 2048 + q * 512 + ln * 8;
        uint4 v = *(const uint4*)(VF + off);
        u16* ve = (u16*)&v;
        ve[0] = f2b(b2f(ve[0]) * c0.x);
        ve[1] = f2b(b2f(ve[1]) * c0.y);
        ve[2] = f2b(b2f(ve[2]) * c0.z);
        ve[3] = f2b(b2f(ve[3]) * c0.w);
        ve[4] = f2b(b2f(ve[4]) * c1.x);
        ve[5] = f2b(b2f(ve[5]) * c1.y);
        ve[6] = f2b(b2f(ve[6]) * c1.z);
        ve[7] = f2b(b2f(ve[7]) * c1.w);
        *(uint4*)(VF2 + off) = v;
    }
}

// ---------------------------------------------------------------------------
// Output: TWO adjacent 32-j tiles per block; each Q/V load feeds both S/PV
// chains. Block 512 thr (8 waves), 8-way i-split. Grid 256. XCD-pinned.
// ---------------------------------------------------------------------------
__global__ __launch_bounds__(512, 2) void out_kernel(const u16* __restrict__ QF,
                                                     const u16* __restrict__ KF,
                                                     const u16* __restrict__ VF2,
                                                     const u32* __restrict__ bitsTT,
                                                     float* __restrict__ out) {
    __shared__ float red[2][4][2048];
    const int bid = blockIdx.x;
    const int b = (bid & 7) >> 1;
    const int u = (bid & 1) * 32 + (bid >> 3);
    const int jt0 = u * 2;
    const int j0 = jt0 * 32;
    const int w = threadIdx.x >> 6, lane = threadIdx.x & 63;
    const int l31 = lane & 31, hf = lane >> 5;

    bf16x8 kfA[4], kfB[4];
    const u16* kbase = KF + (size_t)(b * 128 + jt0) * 2048 + lane * 8;
#pragma unroll
    for (int kt = 0; kt < 4; ++kt) {
        kfA[kt] = ldf(kbase + kt * 512);
        kfB[kt] = ldf(kbase + 2048 + kt * 512);
    }

    const u16* qf0 = QF + (size_t)b * 128 * 2048 + lane * 8;
    const u16* vf0 = VF2 + (size_t)b * 128 * 2048 + lane * 8;

    f32x16 accA0 = {}, accA1 = {}, accB0 = {}, accB1 = {};

    for (int t = 0; t < 16; ++t) {
        const int it = w + t * 8;
        const u16* qb = qf0 + (size_t)it * 2048;
        const u16* vb = vf0 + (size_t)it * 2048;
        u32 mwA = bitsTT[(size_t)it * TT + j0 + l31];
        u32 mwB = bitsTT[(size_t)it * TT + j0 + 32 + l31];

        bf16x8 q0 = ldf(qb), q1 = ldf(qb + 512), q2 = ldf(qb + 1024), q3 = ldf(qb + 1536);
        __builtin_amdgcn_s_setprio(1);
        f32x16 sA = {}, sB = {};
        sA = __builtin_amdgcn_mfma_f32_32x32x16_bf16(q0, kfA[0], sA, 0, 0, 0);
        sB = __builtin_amdgcn_mfma_f32_32x32x16_bf16(q0, kfB[0], sB, 0, 0, 0);
        sA = __builtin_amdgcn_mfma_f32_32x32x16_bf16(q1, kfA[1], sA, 0, 0, 0);
        sB = __builtin_amdgcn_mfma_f32_32x32x16_bf16(q1, kfB[1], sB, 0, 0, 0);
        sA = __builtin_amdgcn_mfma_f32_32x32x16_bf16(q2, kfA[2], sA, 0, 0, 0);
        sB = __builtin_amdgcn_mfma_f32_32x32x16_bf16(q2, kfB[2], sB, 0, 0, 0);
        sA = __builtin_amdgcn_mfma_f32_32x32x16_bf16(q3, kfA[3], sA, 0, 0, 0);
        sB = __builtin_amdgcn_mfma_f32_32x32x16_bf16(q3, kfB[3], sB, 0, 0, 0);
        __builtin_amdgcn_s_setprio(0);

        u32 mrA = __builtin_amdgcn_alignbit(mwA, mwA, hf * 4);  // rotr by 4*hf
        u32 mrB = __builtin_amdgcn_alignbit(mwB, mwB, hf * 4);

        float pA[16], pB[16];
#pragma unroll
        for (int r = 0; r < 16; ++r) {
            const int pos = (r & 3) + 8 * (r >> 2);
            float eA = __builtin_amdgcn_exp2f(sA[r]);
            float eB = __builtin_amdgcn_exp2f(sB[r]);
            pA[r] = ((mrA >> pos) & 1) ? eA : 0.f;
            pB[r] = ((mrB >> pos) & 1) ? eB : 0.f;
        }

        bf16x8 v00 = ldf(vb), v01 = ldf(vb + 512), v10 = ldf(vb + 1024), v11 = ldf(vb + 1536);

#pragma unroll
        for (int k2 = 0; k2 < 2; ++k2) {
            u32 aA  = pk2(pA[8 * k2 + 0], pA[8 * k2 + 1]);
            u32 bA  = pk2(pA[8 * k2 + 2], pA[8 * k2 + 3]);
            u32 cA  = pk2(pA[8 * k2 + 4], pA[8 * k2 + 5]);
            u32 dA  = pk2(pA[8 * k2 + 6], pA[8 * k2 + 7]);
            swap32(aA, cA);
            swap32(bA, dA);
            uint4 awA = {aA, bA, cA, dA};
            bf16x8 paA = __builtin_bit_cast(bf16x8, awA);
            u32 aB  = pk2(pB[8 * k2 + 0], pB[8 * k2 + 1]);
            u32 bB  = pk2(pB[8 * k2 + 2], pB[8 * k2 + 3]);
            u32 cB2 = pk2(pB[8 * k2 + 4], pB[8 * k2 + 5]);
            u32 dB  = pk2(pB[8 * k2 + 6], pB[8 * k2 + 7]);
            swap32(aB, cB2);
            swap32(bB, dB);
            uint4 awB = {aB, bB, cB2, dB};
            bf16x8 paB = __builtin_bit_cast(bf16x8, awB);
            bf16x8 v0 = (k2 == 0) ? v00 : v01;
            bf16x8 v1 = (k2 == 0) ? v10 : v11;
            __builtin_amdgcn_s_setprio(1);
            accA0 = __builtin_amdgcn_mfma_f32_32x32x16_bf16(paA, v0, accA0, 0, 0, 0);
            accB0 = __builtin_amdgcn_mfma_f32_32x32x16_bf16(paB, v0, accB0, 0, 0, 0);
            accA1 = __builtin_amdgcn_mfma_f32_32x32x16_bf16(paA, v1, accA1, 0, 0, 0);
            accB1 = __builtin_amdgcn_mfma_f32_32x32x16_bf16(paB, v1, accB1, 0, 0, 0);
            __builtin_amdgcn_s_setprio(0);
        }
    }

    // staged reduction per j-tile: 8 waves -> 4 -> final sum by all threads
    if (w >= 4) {
#pragma unroll
        for (int r = 0; r < 16; ++r) {
            int jl = (r & 3) + 8 * (r >> 2) + 4 * hf;
            red[0][w - 4][jl * 64 + l31] = accA0[r];
            red[0][w - 4][jl * 64 + 32 + l31] = accA1[r];
            red[1][w - 4][jl * 64 + l31] = accB0[r];
            red[1][w - 4][jl * 64 + 32 + l31] = accB1[r];
        }
    }
    __syncthreads();
    if (w < 4) {
#pragma unroll
        for (int r = 0; r < 16; ++r) {
            int jl = (r & 3) + 8 * (r >> 2) + 4 * hf;
            red[0][w][jl * 64 + l31] += accA0[r];
            red[0][w][jl * 64 + 32 + l31] += accA1[r];
            red[1][w][jl * 64 + l31] += accB0[r];
            red[1][w][jl * 64 + 32 + l31] += accB1[r];
        }
    }
    __syncthreads();
    {
        const int idx = threadIdx.x * 8;          // [0, 4096)
        const int g3 = idx >> 11, e = idx & 2047;
        float vv[8];
#pragma unroll
        for (int q = 0; q < 8; ++q) {
            int ee = e + q;
            float v = red[g3][0][ee] + red[g3][1][ee] + red[g3][2][ee] + red[g3][3][ee];
            vv[q] = v / (1.f + __expf(-v));
        }
        const int jl = e >> 6, hc = e & 63;
        float* dst = out + ((size_t)b * TT + (jt0 + g3) * 32 + jl) * HH + hc;
        *(float4*)dst = make_float4(vv[0], vv[1], vv[2], vv[3]);
        *(float4*)(dst + 4) = make_float4(vv[4], vv[5], vv[6], vv[7]);
    }
}

// ---------------------------------------------------------------------------
extern "C" void kernel_launch(void* const* d_in, const int* in_sizes, int n_in,
                              void* d_out, int out_size, void* d_ws, size_t ws_size,
                              hipStream_t stream) {
    const float* X  = (const float*)d_in[0];
    const int*  dag = (const int*)d_in[1];
    const float* Wk = (const float*)d_in[2];
    const float* Wq = (const float*)d_in[3];
    const float* Wv = (const float*)d_in[4];
    float* out = (float*)d_out;

    char* ws = (char*)d_ws;
    u16*   QF    = (u16*)ws;                                // 0..2 MB (A-frag, pre-scaled)
    u16*   KF    = (u16*)(ws + (2u << 20));                 // 2..4 MB (A-frag)
    u16*   VF    = (u16*)(ws + (4u << 20));                 // 4..6 MB (B-frag, unscaled)
    u16*   VF2   = (u16*)(ws + (6u << 20));                 // 6..8 MB (B-frag, scaled)
    u32*   bits2 = (u32*)(ws + (8u << 20));                 // 8..10 MB  [jt][i]
    u32*   bitsTT= (u32*)(ws + (10u << 20));                // 10..12 MB [it][j]
    u16*   Wt    = (u16*)(ws + (12u << 20));                // 192 KB

    wtr_kernel<<<24, 256, 0, stream>>>(Wq, Wk, Wv, Wt);
    pp_kernel<<<256 + 1366, 384, 0, stream>>>(X, Wt, QF, KF, VF, dag, bits2, bitsTT);
    stats_kernel<<<256, 512, 0, stream>>>(QF, KF, bits2, VF, VF2);
    out_kernel<<<256, 512, 0, stream>>>(QF, KF, VF2, bitsTT, out);
}